// Round 1
// baseline (689.524 us; speedup 1.0000x reference)
//
#include <hip/hip_runtime.h>

// INT4PackedLinear: y[64,28672] = x[64,8192] @ dequant(w_packed, scales) + bias
// Dtype contract (verified R0-R6): x/scales/bias/y are FLOAT32, w_packed int32.
//
// R8: the int32 packing wastes 4x HBM (470 MB read for 117 MB of nibbles).
// New compact_w pre-pass streams w_packed -> uint8 chunks in the EXACT per-block
// (kz,n-block,half-group) DMA order of the main kernel, pre-XOR-swizzled so the
// main kernel's LDS w-reads are <=2-way (free). Main now reads a contiguous
// 64 KB w stream per block; one packed dword = one full 8-elem B-fragment
// (w LDS reads 8->2 per hg per lane, DMA 4->3 instrs per stage). LDS 36->24 KB,
// launch_bounds (256,5) for +1 resident block of latency hiding.

typedef short  short8  __attribute__((ext_vector_type(8)));
typedef float  float4v __attribute__((ext_vector_type(4)));
typedef int    int4v   __attribute__((ext_vector_type(4)));
typedef unsigned int uint4v __attribute__((ext_vector_type(4)));

constexpr int Kd = 8192;
constexpr int Nd = 28672;
constexpr int KSPLIT = 4;           // 4 k-partitions of 2048
constexpr int NBLK = Nd / 64;       // 448 n-blocks

__device__ __forceinline__ unsigned f32_to_bf16_rn(float f) {
    unsigned u = __builtin_bit_cast(unsigned, f);
    return (u + 0x7FFFu + ((u >> 16) & 1u)) >> 16;
}

// async global->LDS DMA: 16B per active lane at (wave-uniform base) + lane*16B.
__device__ __forceinline__ void async16(const void* g, void* l) {
    __builtin_amdgcn_global_load_lds(
        (const __attribute__((address_space(1))) unsigned*)g,
        (__attribute__((address_space(3))) unsigned*)l, 16, 0, 0);
}

// ---- y := bias broadcast over 64 rows ----
__global__ __launch_bounds__(256)
void init_y_kernel(const float* __restrict__ bias, float* __restrict__ y) {
    const int gid = blockIdx.x * 256 + threadIdx.x;       // 458752 = 64*7168
    const int m  = gid / (Nd / 4);
    const int nq = gid % (Nd / 4);
    ((float4v*)y)[(long)m * (Nd / 4) + nq] = ((const float4v*)bias)[nq];
}

// ---- x f32 -> bf16 into workspace ----
__global__ __launch_bounds__(256)
void cvt_x_kernel(const float* __restrict__ x, unsigned short* __restrict__ o) {
    const int i = (blockIdx.x * 256 + threadIdx.x) * 8;
    float4v a = *(const float4v*)(x + i);
    float4v b = *(const float4v*)(x + i + 4);
    union { unsigned short s[8]; short8 v; } r;
    #pragma unroll
    for (int j = 0; j < 4; ++j) {
        r.s[j]     = (unsigned short)f32_to_bf16_rn(a[j]);
        r.s[4 + j] = (unsigned short)f32_to_bf16_rn(b[j]);
    }
    *(short8*)(o + i) = r.v;
}

// ---- w int32 -> byte-packed streaming chunks ----
// Chunk (kz, b, hg) = 512 dwords (2 KB): dword (quad, col) holds bytes j=0..3 =
// low byte of wp[kz*1024 + hg*32 + quad*4 + j][b*64 + col], stored at offset
// quad*64 + (col ^ ((quad&3)<<4))  (bank-free for the main kernel's read).
// Chunk order = ((kz*448 + b)*32 + hg): each main block reads 64 KB contiguous.
__global__ __launch_bounds__(256)
void compact_w_kernel(const int* __restrict__ wp, unsigned* __restrict__ cw) {
    const int b = blockIdx.x, kz = blockIdx.y, z = blockIdx.z;
    const int t = threadIdx.x;
    const int hg = 2 * z + (t >> 7);          // two chunks per block
    const int u = t & 127, quad = u >> 4, cc = u & 15;
    const int kpair0 = kz * 1024 + hg * 32 + quad * 4;
    const int* src = wp + (long)kpair0 * Nd + b * 64 + 4 * cc;
    int4v r0 = *(const int4v*)(src);
    int4v r1 = *(const int4v*)(src + Nd);
    int4v r2 = *(const int4v*)(src + 2 * Nd);
    int4v r3 = *(const int4v*)(src + 3 * Nd);
    uint4v o;
    #pragma unroll
    for (int d = 0; d < 4; ++d)
        o[d] = (unsigned)(r0[d] & 0xFF) | ((unsigned)(r1[d] & 0xFF) << 8)
             | ((unsigned)(r2[d] & 0xFF) << 16) | ((unsigned)(r3[d] & 0xFF) << 24);
    unsigned* dst = cw + (long)((kz * NBLK + b) * 32 + hg) * 512
                       + quad * 64 + ((4 * cc) ^ ((quad & 3) << 4));
    *(uint4v*)dst = o;
}

// ---- main (compact w): grid (448, 4), block 256 ----
__global__ __launch_bounds__(256, 5)
void int4_main_cw_kernel(const unsigned short* __restrict__ xw,
                         const unsigned*       __restrict__ cw,
                         const float*          __restrict__ scales,
                         float*                __restrict__ y)
{
    __shared__ unsigned wb0[512],  wb1[512];    // w half-group: 2 KB byte-packed
    __shared__ unsigned xb0[2048], xb1[2048];   // x half-group: 64 m x 8 chunks
    __shared__ unsigned sb[1024];               // scales: 16 groups x 64 n (f32)

    const int t = threadIdx.x, lane = t & 63, wv = t >> 6;
    const int q = lane >> 4, c = lane & 15;
    const int n0 = blockIdx.x * 64, kz = blockIdx.y;

    // ---- per-lane DMA source pointers ----
    // w: contiguous chunk stream; wave wv copies bytes [wv*512, wv*512+512) of
    // each 2 KB chunk with lanes 0..31 (16 B/lane).
    const unsigned* wsrc = cw + (long)((kz * NBLK + blockIdx.x) * 32) * 512
                              + wv * 128 + lane * 4;      // dwords (lane<32)
    // x instr i: s = wv*128 + i*64 + lane ; m = s>>3 ; kq = (s&7)^(m&7)
    const unsigned short* xsrc0; const unsigned short* xsrc1;
    {
        int s0 = wv * 128 + 0 * 64 + lane, m0 = s0 >> 3, k0 = (s0 & 7) ^ (m0 & 7);
        int s1 = wv * 128 + 1 * 64 + lane, m1 = s1 >> 3, k1 = (s1 & 7) ^ (m1 & 7);
        xsrc0 = xw + (long)m0 * Kd + kz * 2048 + k0 * 8;
        xsrc1 = xw + (long)m1 * Kd + kz * 2048 + k1 * 8;
    }
    const int ldof = wv * 512;   // dwords; instr1 adds +256

    // ---- prologue: scales (4KB, one DMA) + half-group 0 ----
    {
        const float* ssrc = scales + (long)(kz * 16 + (t >> 4)) * Nd + n0 + (t & 15) * 4;
        async16(ssrc, sb + wv * 256);
    }
    if (lane < 32) async16(wsrc, wb0 + wv * 128);
    async16(xsrc0, xb0 + ldof);
    async16(xsrc1, xb0 + ldof + 256);

    float4v acc[4] = {};

    auto stage = [&](int hg, unsigned* wbuf, unsigned* xbuf) {
        const long xof = (long)hg * 64;         // 64 k elems per half-group
        if (lane < 32) async16(wsrc + (long)hg * 512, wbuf + wv * 128);
        async16(xsrc0 + xof, xbuf + ldof);
        async16(xsrc1 + xof, xbuf + ldof + 256);
    };

    auto compute = [&](const unsigned* wbuf, const unsigned* xbuf, int g) {
        const float s   = __builtin_bit_cast(float, sb[g * 64 + wv * 16 + c]);
        const float m8s = -8.0f * s;
        #pragma unroll
        for (int it = 0; it < 2; ++it) {
            // one dword = bytes for kpairs (it*4+q)*4 .. +3 at col wv*16+c
            unsigned v = wbuf[(it * 4 + q) * 64 + ((wv * 16 + c) ^ (q << 4))];
            union { short8 h; unsigned u[4]; } bu;
            #pragma unroll
            for (int j = 0; j < 4; ++j) {
                unsigned b = (v >> (8 * j)) & 0xFFu;
                float lo = fmaf((float)(b & 15u), s, m8s);          // ==((b&15)-8)*s
                float hi = fmaf((float)((b >> 4) & 15u), s, m8s);
                bu.u[j] = f32_to_bf16_rn(lo) | (f32_to_bf16_rn(hi) << 16);
            }
            #pragma unroll
            for (int mt = 0; mt < 4; ++mt) {
                int m = mt * 16 + c;
                int slot = m * 8 + ((it * 4 + q) ^ (c & 7));        // XOR-swizzled
                short8 a = *(const short8*)(xbuf + slot * 4);
                acc[mt] = __builtin_amdgcn_mfma_f32_16x16x32_bf16(a, bu.h, acc[mt], 0, 0, 0);
            }
        }
    };

    for (int hgp = 0; hgp < 16; ++hgp) {
        const int hg = 2 * hgp;
        // even half-group: compute buf0(hg); stage hg+1 -> buf1
        stage(hg + 1, wb1, xb1);
        asm volatile("s_waitcnt vmcnt(3)\ns_barrier" ::: "memory");
        compute(wb0, xb0, hgp);
        asm volatile("s_waitcnt lgkmcnt(0)\ns_barrier" ::: "memory");
        // odd half-group: compute buf1(hg+1); stage hg+2 -> buf0
        if (hgp < 15) {
            stage(hg + 2, wb0, xb0);
            asm volatile("s_waitcnt vmcnt(3)\ns_barrier" ::: "memory");
        } else {
            asm volatile("s_waitcnt vmcnt(0)\ns_barrier" ::: "memory");
        }
        compute(wb1, xb1, hgp);
        asm volatile("s_waitcnt lgkmcnt(0)\ns_barrier" ::: "memory");
    }

    // ---- epilogue: C/D row m = mt*16 + q*4 + r, col n = n0 + wv*16 + c ----
    const int nw = n0 + wv * 16 + c;
    #pragma unroll
    for (int mt = 0; mt < 4; ++mt)
        #pragma unroll
        for (int r = 0; r < 4; ++r)
            atomicAdd(&y[(long)(mt * 16 + q * 4 + r) * Nd + nw], acc[mt][r]);
}

// ---- main (direct int32 w, medium-ws fallback): verified R7 structure ----
__global__ __launch_bounds__(256, 4)
void int4_main_kernel(const unsigned short* __restrict__ xw,
                      const int*            __restrict__ wp,
                      const float*          __restrict__ scales,
                      float*                __restrict__ y)
{
    __shared__ unsigned wb0[2048], wb1[2048];
    __shared__ unsigned xb0[2048], xb1[2048];
    __shared__ unsigned sb[1024];

    const int t = threadIdx.x, lane = t & 63, wv = t >> 6;
    const int q = lane >> 4, c = lane & 15;
    const int l4 = lane >> 4, l15 = lane & 15;
    const int n0 = blockIdx.x * 64, kz = blockIdx.y;

    const int* wsrc0; const int* wsrc1;
    {
        int r0 = wv * 8 + 0 * 4 + l4, c0 = (l15 * 4) ^ (((wv * 2 + 0) & 3) << 4);
        int r1 = wv * 8 + 1 * 4 + l4, c1 = (l15 * 4) ^ (((wv * 2 + 1) & 3) << 4);
        wsrc0 = wp + (long)(kz * 1024 + r0) * Nd + n0 + c0;
        wsrc1 = wp + (long)(kz * 1024 + r1) * Nd + n0 + c1;
    }
    const unsigned short* xsrc0; const unsigned short* xsrc1;
    {
        int s0 = wv * 128 + 0 * 64 + lane, m0 = s0 >> 3, k0 = (s0 & 7) ^ (m0 & 7);
        int s1 = wv * 128 + 1 * 64 + lane, m1 = s1 >> 3, k1 = (s1 & 7) ^ (m1 & 7);
        xsrc0 = xw + (long)m0 * Kd + kz * 2048 + k0 * 8;
        xsrc1 = xw + (long)m1 * Kd + kz * 2048 + k1 * 8;
    }
    const int ldof = wv * 512;

    {
        const float* ssrc = scales + (long)(kz * 16 + (t >> 4)) * Nd + n0 + (t & 15) * 4;
        async16(ssrc, sb + wv * 256);
    }
    async16(wsrc0, wb0 + ldof);
    async16(wsrc1, wb0 + ldof + 256);
    async16(xsrc0, xb0 + ldof);
    async16(xsrc1, xb0 + ldof + 256);

    float4v acc[4] = {};

    auto stage = [&](int hg, unsigned* wbuf, unsigned* xbuf) {
        const long wof = (long)hg * 32 * Nd;
        const long xof = (long)hg * 64;
        async16(wsrc0 + wof, wbuf + ldof);
        async16(wsrc1 + wof, wbuf + ldof + 256);
        async16(xsrc0 + xof, xbuf + ldof);
        async16(xsrc1 + xof, xbuf + ldof + 256);
    };

    auto compute = [&](const unsigned* wbuf, const unsigned* xbuf, int g) {
        const float s   = __builtin_bit_cast(float, sb[g * 64 + wv * 16 + c]);
        const float m8s = -8.0f * s;
        #pragma unroll
        for (int it = 0; it < 2; ++it) {
            union { short8 h; unsigned u[4]; } bu;
            #pragma unroll
            for (int i = 0; i < 4; ++i) {
                unsigned v = wbuf[(it * 16 + q * 4 + i) * 64 + ((wv * 16 + c) ^ (q << 4))];
                float lo = fmaf((float)(v & 15u), s, m8s);
                float hi = fmaf((float)((v >> 4) & 15u), s, m8s);
                bu.u[i] = f32_to_bf16_rn(lo) | (f32_to_bf16_rn(hi) << 16);
            }
            #pragma unroll
            for (int mt = 0; mt < 4; ++mt) {
                int m = mt * 16 + c;
                int slot = m * 8 + ((it * 4 + q) ^ (c & 7));
                short8 a = *(const short8*)(xbuf + slot * 4);
                acc[mt] = __builtin_amdgcn_mfma_f32_16x16x32_bf16(a, bu.h, acc[mt], 0, 0, 0);
            }
        }
    };

    for (int hgp = 0; hgp < 16; ++hgp) {
        const int hg = 2 * hgp;
        stage(hg + 1, wb1, xb1);
        asm volatile("s_waitcnt vmcnt(4)\ns_barrier" ::: "memory");
        compute(wb0, xb0, hgp);
        asm volatile("s_waitcnt lgkmcnt(0)\ns_barrier" ::: "memory");
        if (hgp < 15) {
            stage(hg + 2, wb0, xb0);
            asm volatile("s_waitcnt vmcnt(4)\ns_barrier" ::: "memory");
        } else {
            asm volatile("s_waitcnt vmcnt(0)\ns_barrier" ::: "memory");
        }
        compute(wb1, xb1, hgp);
        asm volatile("s_waitcnt lgkmcnt(0)\ns_barrier" ::: "memory");
    }

    const int nw = n0 + wv * 16 + c;
    #pragma unroll
    for (int mt = 0; mt < 4; ++mt)
        #pragma unroll
        for (int r = 0; r < 4; ++r)
            atomicAdd(&y[(long)(mt * 16 + q * 4 + r) * Nd + nw], acc[mt][r]);
}

// ---- fallback main (no ws): R4 structure, inline f32->bf16 A loads ----
__global__ __launch_bounds__(256, 6)
void int4_main_nows_kernel(const float* __restrict__ xf,
                           const int*   __restrict__ wp,
                           const float* __restrict__ scales,
                           float*       __restrict__ y)
{
    constexpr int LDS_STRIDE = 68;
    __shared__ unsigned lds_w[64 * LDS_STRIDE];
    const int t = threadIdx.x, lane = t & 63, wv = t >> 6;
    const int q = lane >> 4, c = lane & 15;
    const int n0 = blockIdx.x * 64, kz = blockIdx.y;
    const int sr = t >> 4, ss = t & 15;
    const int*   wp_b = wp + (long)(kz * 1024 + sr) * Nd + n0 + 4 * ss;
    const float* sc_b = scales + (long)(kz * 16) * Nd + n0 + 4 * ss;
    const float* xf_b = xf + (long)c * Kd + kz * 2048 + q * 8;
    float4v acc[4] = {};

    for (int g = 0; g < 16; ++g) {
        const float4v s4 = *(const float4v*)(sc_b + (long)g * Nd);
        const int* wg = wp_b + (long)g * 64 * Nd;
        #pragma unroll
        for (int i = 0; i < 4; ++i) {
            int4v v = *(const int4v*)(wg + (long)i * 16 * Nd);
            uint4v pk;
            #pragma unroll
            for (int j = 0; j < 4; ++j) {
                float lo = (float)((v[j] & 15) - 8) * s4[j];
                float hi = (float)(((v[j] >> 4) & 15) - 8) * s4[j];
                pk[j] = f32_to_bf16_rn(lo) | (f32_to_bf16_rn(hi) << 16);
            }
            *(uint4v*)&lds_w[(i * 16 + sr) * LDS_STRIDE + 4 * ss] = pk;
        }
        __syncthreads();
        const float* xg = xf_b + g * 128;
        #pragma unroll
        for (int it = 0; it < 4; ++it) {
            union { short8 h; unsigned u[4]; } bu;
            #pragma unroll
            for (int i = 0; i < 4; ++i)
                bu.u[i] = lds_w[(it * 16 + q * 4 + i) * LDS_STRIDE + wv * 16 + c];
            const short8 b = bu.h;
            const float* xk = xg + it * 32;
            #pragma unroll
            for (int mt = 0; mt < 4; ++mt) {
                float4v a0 = *(const float4v*)(xk + (long)mt * 16 * Kd);
                float4v a1 = *(const float4v*)(xk + (long)mt * 16 * Kd + 4);
                union { unsigned short s[8]; short8 v; } r;
                #pragma unroll
                for (int j = 0; j < 4; ++j) {
                    r.s[j]     = (unsigned short)f32_to_bf16_rn(a0[j]);
                    r.s[4 + j] = (unsigned short)f32_to_bf16_rn(a1[j]);
                }
                acc[mt] = __builtin_amdgcn_mfma_f32_16x16x32_bf16(r.v, b, acc[mt], 0, 0, 0);
            }
        }
        __syncthreads();
    }
    const int nw = n0 + wv * 16 + c;
    #pragma unroll
    for (int mt = 0; mt < 4; ++mt)
        #pragma unroll
        for (int r = 0; r < 4; ++r)
            atomicAdd(&y[(long)(mt * 16 + q * 4 + r) * Nd + nw], acc[mt][r]);
}

extern "C" void kernel_launch(void* const* d_in, const int* in_sizes, int n_in,
                              void* d_out, int out_size, void* d_ws, size_t ws_size,
                              hipStream_t stream) {
    const float* x      = (const float*)d_in[0];
    const int*   wp     = (const int*)d_in[1];
    const float* scales = (const float*)d_in[2];
    const float* bias   = (const float*)d_in[3];
    float*       y      = (float*)d_out;

    init_y_kernel<<<dim3(1792), dim3(256), 0, stream>>>(bias, y);

    const size_t xb_bytes = (size_t)64 * Kd * sizeof(unsigned short); // 1 MB
    const size_t cw_bytes = (size_t)(Kd / 2) * Nd;                    // 112 MB
    dim3 grid(NBLK, KSPLIT);   // (448, 4) -> 1792 blocks
    dim3 block(256);

    if (ws_size >= xb_bytes + cw_bytes) {
        unsigned short* xb = (unsigned short*)d_ws;
        unsigned* cw = (unsigned*)((char*)d_ws + xb_bytes);
        cvt_x_kernel<<<dim3(256), dim3(256), 0, stream>>>(x, xb);
        compact_w_kernel<<<dim3(NBLK, KSPLIT, 16), dim3(256), 0, stream>>>(wp, cw);
        int4_main_cw_kernel<<<grid, block, 0, stream>>>(xb, cw, scales, y);
    } else if (ws_size >= xb_bytes) {
        unsigned short* xb = (unsigned short*)d_ws;
        cvt_x_kernel<<<dim3(256), dim3(256), 0, stream>>>(x, xb);
        int4_main_kernel<<<grid, block, 0, stream>>>(xb, wp, scales, y);
    } else {
        int4_main_nows_kernel<<<grid, block, 0, stream>>>(x, wp, scales, y);
    }
}

// Round 3
// 627.241 us; speedup vs baseline: 1.0993x; 1.0993x over previous
//
#include <hip/hip_runtime.h>

// INT4PackedLinear: y[64,28672] = x[64,8192] @ dequant(w_packed, scales) + bias
// Dtype contract (verified R0-R6): x/scales/bias/y are FLOAT32, w_packed int32.
//
// R8 post-mortem: compact-w prepass (4x byte cut) gained main only ~40us ->
// main is NOT HBM-bound; it is stalled on the distance-1 prefetch (each phase
// eats a full LDS-DMA round trip). Reverted.
// R9 (re-run; R2 bench was an infra failure, no data): 3-slot ring buffer,
// prefetch distance 2: stage(p+2) issued while computing p, counted
// s_waitcnt vmcnt(8) (two 4-load stages in flight across barriers; never
// drained in the main loop). Loop body explicitly 3-phase-unrolled so all
// slot pointers are compile-time (no reliance on #pragma unroll; rule #20).
// setprio(1) around MFMA clusters. launch_bounds(256,3): LDS 52KB ->
// 3 blk/CU, VGPR cap ~170.

typedef short  short8  __attribute__((ext_vector_type(8)));
typedef float  float4v __attribute__((ext_vector_type(4)));
typedef int    int4v   __attribute__((ext_vector_type(4)));
typedef unsigned int uint4v __attribute__((ext_vector_type(4)));

constexpr int Kd = 8192;
constexpr int Nd = 28672;
constexpr int KSPLIT = 4;           // 4 k-partitions of 2048

__device__ __forceinline__ unsigned f32_to_bf16_rn(float f) {
    unsigned u = __builtin_bit_cast(unsigned, f);
    return (u + 0x7FFFu + ((u >> 16) & 1u)) >> 16;
}

// async global->LDS DMA: 16B per lane at (wave-uniform base) + lane*16B.
__device__ __forceinline__ void async16(const void* g, void* l) {
    __builtin_amdgcn_global_load_lds(
        (const __attribute__((address_space(1))) unsigned*)g,
        (__attribute__((address_space(3))) unsigned*)l, 16, 0, 0);
}

// ---- y := bias broadcast over 64 rows ----
__global__ __launch_bounds__(256)
void init_y_kernel(const float* __restrict__ bias, float* __restrict__ y) {
    const int gid = blockIdx.x * 256 + threadIdx.x;       // 458752 = 64*7168
    const int m  = gid / (Nd / 4);
    const int nq = gid % (Nd / 4);
    ((float4v*)y)[(long)m * (Nd / 4) + nq] = ((const float4v*)bias)[nq];
}

// ---- x f32 -> bf16 into workspace ----
__global__ __launch_bounds__(256)
void cvt_x_kernel(const float* __restrict__ x, unsigned short* __restrict__ o) {
    const int i = (blockIdx.x * 256 + threadIdx.x) * 8;
    float4v a = *(const float4v*)(x + i);
    float4v b = *(const float4v*)(x + i + 4);
    union { unsigned short s[8]; short8 v; } r;
    #pragma unroll
    for (int j = 0; j < 4; ++j) {
        r.s[j]     = (unsigned short)f32_to_bf16_rn(a[j]);
        r.s[4 + j] = (unsigned short)f32_to_bf16_rn(b[j]);
    }
    *(short8*)(o + i) = r.v;
}

// ---- main: grid (448, 4), block 256, 3-slot ring, distance-2 prefetch ----
__global__ __launch_bounds__(256, 3)
void int4_main_kernel(const unsigned short* __restrict__ xw,
                      const int*            __restrict__ wp,
                      const float*          __restrict__ scales,
                      float*                __restrict__ y)
{
    // Separate objects so the waitcnt pass can disambiguate DMA targets.
    __shared__ unsigned wbA[2048], wbB[2048], wbC[2048]; // w half-group: 32 r x 64 n
    __shared__ unsigned xbA[2048], xbB[2048], xbC[2048]; // x half-group: 64 m x 8 ch
    __shared__ unsigned sb[1024];                        // scales: 16 g x 64 n (f32)

    const int t = threadIdx.x, lane = t & 63, wv = t >> 6;
    const int q = lane >> 4, c = lane & 15;
    const int l4 = lane >> 4, l15 = lane & 15;
    const int n0 = blockIdx.x * 64, kz = blockIdx.y;

    // ---- per-lane DMA source pointers (identical to verified R7 layout) ----
    // w instr i: row = wv*8 + i*4 + l4 ; col = (l15*4) ^ (((wv*2+i)&3)<<4)
    const int* wsrc0; const int* wsrc1;
    {
        int r0 = wv * 8 + 0 * 4 + l4, c0 = (l15 * 4) ^ (((wv * 2 + 0) & 3) << 4);
        int r1 = wv * 8 + 1 * 4 + l4, c1 = (l15 * 4) ^ (((wv * 2 + 1) & 3) << 4);
        wsrc0 = wp + (long)(kz * 1024 + r0) * Nd + n0 + c0;
        wsrc1 = wp + (long)(kz * 1024 + r1) * Nd + n0 + c1;
    }
    // x instr i: s = wv*128 + i*64 + lane ; m = s>>3 ; kq = (s&7)^(m&7)
    const unsigned short* xsrc0; const unsigned short* xsrc1;
    {
        int s0 = wv * 128 + 0 * 64 + lane, m0 = s0 >> 3, k0 = (s0 & 7) ^ (m0 & 7);
        int s1 = wv * 128 + 1 * 64 + lane, m1 = s1 >> 3, k1 = (s1 & 7) ^ (m1 & 7);
        xsrc0 = xw + (long)m0 * Kd + kz * 2048 + k0 * 8;
        xsrc1 = xw + (long)m1 * Kd + kz * 2048 + k1 * 8;
    }
    const int ldof = wv * 512;   // dwords; instr1 adds +256

    auto stage = [&](int hg, unsigned* wbuf, unsigned* xbuf) {
        const long wof = (long)hg * 32 * Nd;    // 32 packed rows per half-group
        const long xof = (long)hg * 64;         // 64 k elems per half-group
        async16(wsrc0 + wof, wbuf + ldof);
        async16(wsrc1 + wof, wbuf + ldof + 256);
        async16(xsrc0 + xof, xbuf + ldof);
        async16(xsrc1 + xof, xbuf + ldof + 256);
    };

    // ---- prologue: scales (4KB, 1 DMA) + half-groups 0,1 (distance-2 fill) ----
    {
        const float* ssrc = scales + (long)(kz * 16 + (t >> 4)) * Nd + n0 + (t & 15) * 4;
        async16(ssrc, sb + wv * 256);
    }
    stage(0, wbA, xbA);
    stage(1, wbB, xbB);

    float4v acc[4] = {};

    auto compute = [&](const unsigned* wbuf, const unsigned* xbuf, int g) {
        const float s   = __builtin_bit_cast(float, sb[g * 64 + wv * 16 + c]);
        const float m8s = -8.0f * s;
        #pragma unroll
        for (int it = 0; it < 2; ++it) {
            union { short8 h; unsigned u[4]; } bu;
            #pragma unroll
            for (int i = 0; i < 4; ++i) {
                unsigned v = wbuf[(it * 16 + q * 4 + i) * 64 + ((wv * 16 + c) ^ (q << 4))];
                float lo = fmaf((float)(v & 15u), s, m8s);          // ==((v&15)-8)*s
                float hi = fmaf((float)((v >> 4) & 15u), s, m8s);
                bu.u[i] = f32_to_bf16_rn(lo) | (f32_to_bf16_rn(hi) << 16);
            }
            __builtin_amdgcn_s_setprio(1);
            #pragma unroll
            for (int mt = 0; mt < 4; ++mt) {
                int m = mt * 16 + c;
                int slot = m * 8 + ((it * 4 + q) ^ (c & 7));        // XOR-swizzled
                short8 a = *(const short8*)(xbuf + slot * 4);
                acc[mt] = __builtin_amdgcn_mfma_f32_16x16x32_bf16(a, bu.h, acc[mt], 0, 0, 0);
            }
            __builtin_amdgcn_s_setprio(0);
        }
    };

    // ---- main loop: phase ph computes slot ph%3, stages hg=ph+2 into (ph+2)%3.
    // vmcnt(8): stages ph+1, ph+2 (4 loads each) stay in flight across barriers.
    // Explicit 3-phase body: all slot pointers compile-time (A,B,C named).
    for (int g3 = 0; g3 < 10; ++g3) {
        const int ph = 3 * g3;
        // ph: compute A, stage -> C
        stage(ph + 2, wbC, xbC);
        asm volatile("s_waitcnt vmcnt(8)\ns_barrier" ::: "memory");
        compute(wbA, xbA, ph >> 1);
        asm volatile("s_waitcnt lgkmcnt(0)\ns_barrier" ::: "memory");
        // ph+1: compute B, stage -> A
        stage(ph + 3, wbA, xbA);
        asm volatile("s_waitcnt vmcnt(8)\ns_barrier" ::: "memory");
        compute(wbB, xbB, (ph + 1) >> 1);
        asm volatile("s_waitcnt lgkmcnt(0)\ns_barrier" ::: "memory");
        // ph+2: compute C, stage -> B
        stage(ph + 4, wbB, xbB);
        asm volatile("s_waitcnt vmcnt(8)\ns_barrier" ::: "memory");
        compute(wbC, xbC, (ph + 2) >> 1);
        asm volatile("s_waitcnt lgkmcnt(0)\ns_barrier" ::: "memory");
    }
    // phases 0..29 done; hg30 is in A (staged at ph=28), hg31 in B (ph=29).
    // ph=30: 8 loads outstanding -> retire stage 30 only.
    asm volatile("s_waitcnt vmcnt(4)\ns_barrier" ::: "memory");
    compute(wbA, xbA, 15);
    asm volatile("s_waitcnt lgkmcnt(0)\ns_barrier" ::: "memory");
    // ph=31: drain last stage.
    asm volatile("s_waitcnt vmcnt(0)\ns_barrier" ::: "memory");
    compute(wbB, xbB, 15);

    // ---- epilogue: C/D row m = mt*16 + q*4 + r, col n = n0 + wv*16 + c ----
    const int nw = n0 + wv * 16 + c;
    #pragma unroll
    for (int mt = 0; mt < 4; ++mt)
        #pragma unroll
        for (int r = 0; r < 4; ++r)
            atomicAdd(&y[(long)(mt * 16 + q * 4 + r) * Nd + nw], acc[mt][r]);
}

// ---- fallback main (no ws): R4 structure, inline f32->bf16 A loads ----
__global__ __launch_bounds__(256, 6)
void int4_main_nows_kernel(const float* __restrict__ xf,
                           const int*   __restrict__ wp,
                           const float* __restrict__ scales,
                           float*       __restrict__ y)
{
    constexpr int LDS_STRIDE = 68;
    __shared__ unsigned lds_w[64 * LDS_STRIDE];
    const int t = threadIdx.x, lane = t & 63, wv = t >> 6;
    const int q = lane >> 4, c = lane & 15;
    const int n0 = blockIdx.x * 64, kz = blockIdx.y;
    const int sr = t >> 4, ss = t & 15;
    const int*   wp_b = wp + (long)(kz * 1024 + sr) * Nd + n0 + 4 * ss;
    const float* sc_b = scales + (long)(kz * 16) * Nd + n0 + 4 * ss;
    const float* xf_b = xf + (long)c * Kd + kz * 2048 + q * 8;
    float4v acc[4] = {};

    for (int g = 0; g < 16; ++g) {
        const float4v s4 = *(const float4v*)(sc_b + (long)g * Nd);
        const int* wg = wp_b + (long)g * 64 * Nd;
        #pragma unroll
        for (int i = 0; i < 4; ++i) {
            int4v v = *(const int4v*)(wg + (long)i * 16 * Nd);
            uint4v pk;
            #pragma unroll
            for (int j = 0; j < 4; ++j) {
                float lo = (float)((v[j] & 15) - 8) * s4[j];
                float hi = (float)(((v[j] >> 4) & 15) - 8) * s4[j];
                pk[j] = f32_to_bf16_rn(lo) | (f32_to_bf16_rn(hi) << 16);
            }
            *(uint4v*)&lds_w[(i * 16 + sr) * LDS_STRIDE + 4 * ss] = pk;
        }
        __syncthreads();
        const float* xg = xf_b + g * 128;
        #pragma unroll
        for (int it = 0; it < 4; ++it) {
            union { short8 h; unsigned u[4]; } bu;
            #pragma unroll
            for (int i = 0; i < 4; ++i)
                bu.u[i] = lds_w[(it * 16 + q * 4 + i) * LDS_STRIDE + wv * 16 + c];
            const short8 b = bu.h;
            const float* xk = xg + it * 32;
            #pragma unroll
            for (int mt = 0; mt < 4; ++mt) {
                float4v a0 = *(const float4v*)(xk + (long)mt * 16 * Kd);
                float4v a1 = *(const float4v*)(xk + (long)mt * 16 * Kd + 4);
                union { unsigned short s[8]; short8 v; } r;
                #pragma unroll
                for (int j = 0; j < 4; ++j) {
                    r.s[j]     = (unsigned short)f32_to_bf16_rn(a0[j]);
                    r.s[4 + j] = (unsigned short)f32_to_bf16_rn(a1[j]);
                }
                acc[mt] = __builtin_amdgcn_mfma_f32_16x16x32_bf16(r.v, b, acc[mt], 0, 0, 0);
            }
        }
        __syncthreads();
    }
    const int nw = n0 + wv * 16 + c;
    #pragma unroll
    for (int mt = 0; mt < 4; ++mt)
        #pragma unroll
        for (int r = 0; r < 4; ++r)
            atomicAdd(&y[(long)(mt * 16 + q * 4 + r) * Nd + nw], acc[mt][r]);
}

extern "C" void kernel_launch(void* const* d_in, const int* in_sizes, int n_in,
                              void* d_out, int out_size, void* d_ws, size_t ws_size,
                              hipStream_t stream) {
    const float* x      = (const float*)d_in[0];
    const int*   wp     = (const int*)d_in[1];
    const float* scales = (const float*)d_in[2];
    const float* bias   = (const float*)d_in[3];
    float*       y      = (float*)d_out;

    init_y_kernel<<<dim3(1792), dim3(256), 0, stream>>>(bias, y);

    const size_t xb_bytes = (size_t)64 * Kd * sizeof(unsigned short); // 1 MB
    dim3 grid(Nd / 64, KSPLIT);   // (448, 4) -> 1792 blocks
    dim3 block(256);

    if (ws_size >= xb_bytes) {
        unsigned short* xb = (unsigned short*)d_ws;
        cvt_x_kernel<<<dim3(256), dim3(256), 0, stream>>>(x, xb);
        int4_main_kernel<<<grid, block, 0, stream>>>(xb, wp, scales, y);
    } else {
        int4_main_nows_kernel<<<grid, block, 0, stream>>>(x, wp, scales, y);
    }
}